// Round 8
// baseline (604.184 us; speedup 1.0000x reference)
//
#include <hip/hip_runtime.h>
#include <hip/hip_bf16.h>
#include <hip/hip_cooperative_groups.h>

namespace cg = cooperative_groups;

// GraphSAGE 3-layer. Round 8:
//  - ONE cooperative kernel does zero+pack / hist / scan / fill (was 6 kernels)
//  - h0 stored bf16 (gemm0 epilogue); layer-1 GEMM stages A from mean1|h0 directly
//  Dispatches: csr_coop, gather0, gemm0, gather1, gemm1, final = 6.

typedef short bf16x8 __attribute__((ext_vector_type(8)));
typedef float f32x4 __attribute__((ext_vector_type(4)));

static __device__ __forceinline__ unsigned short f2bf(float f) {
  unsigned u = __float_as_uint(f);
  unsigned r = u + 0x7FFFu + ((u >> 16) & 1u);  // RNE
  return (unsigned short)(r >> 16);
}
static __device__ __forceinline__ float bf2f(unsigned short v) {
  return __uint_as_float((unsigned)v << 16);
}

// ---- int-workspace layout (offsets in ints, from iw base) ----
#define ROW0_OFF 0
#define ROW1_OFF 60001
#define ROW2_OFF 66002
#define CNT_OFF  67027     // cnt0|cnt1|cnt2 contiguous (67024)
#define CUR0_OFF 134051
#define CUR1_OFF 194051
#define CUR2_OFF 200051
#define SS0_OFF  201075
#define SS1_OFF  1101075
#define SS2_OFF  1161075

struct TileGeom { int tin, goff, n, tbeg, T; };
static __device__ __forceinline__ TileGeom tile_geom(int b) {
  TileGeom g;
  if (b < 118)      { g.tin = b;       g.goff = 0;     g.n = 60000; g.tbeg = 0;   g.T = 118; }
  else if (b < 130) { g.tin = b - 118; g.goff = 60000; g.n = 6000;  g.tbeg = 118; g.T = 12; }
  else              { g.tin = b - 130; g.goff = 66000; g.n = 1024;  g.tbeg = 130; g.T = 2; }
  return g;
}

// ---------------- cooperative CSR + weight-pack kernel ----------------
__global__ __launch_bounds__(256) void csr_coop_k(
    const int* __restrict__ d0, const int* __restrict__ d1, const int* __restrict__ d2,
    const int* __restrict__ s0, const int* __restrict__ s1, const int* __restrict__ s2,
    int* __restrict__ iw,
    const float* __restrict__ Wl0, const float* __restrict__ Wr0,
    unsigned short* __restrict__ bm0,
    const float* __restrict__ Wl1, const float* __restrict__ Wr1,
    unsigned short* __restrict__ bm1,
    int E0, int E1, int E2) {
  cg::grid_group grid = cg::this_grid();
  __shared__ int sld[256];
  const int tid = threadIdx.x;
  const int gsz = gridDim.x * 256;
  const int gtid = blockIdx.x * 256 + tid;
  int* cnt = iw + CNT_OFF;
  const int ET = E0 + E1 + E2;

  // ---- Phase A: zero cnt + pack weights (independent work) ----
  for (int i = gtid; i < 67024; i += gsz) cnt[i] = 0;
  for (int i = gtid; i < 57344 + 131072; i += gsz) {
    if (i < 57344) {
      int k = i >> 8, n = i & 255;
      float v = 0.f;
      if (k < 100) v = Wl0[(size_t)k * 256 + n];
      else if (k >= 112 && k < 212) v = Wr0[(size_t)(k - 112) * 256 + n];
      bm0[(((size_t)(k >> 3) * 256) + n) * 8 + (k & 7)] = f2bf(v);
    } else {
      int j = i - 57344;
      int k = j >> 8, n = j & 255;
      float v = (k < 256) ? Wl1[(size_t)k * 256 + n] : Wr1[(size_t)(k - 256) * 256 + n];
      bm1[(((size_t)(k >> 3) * 256) + n) * 8 + (k & 7)] = f2bf(v);
    }
  }
  grid.sync();

  // ---- Phase B: histogram ----
  for (int t = gtid; t < ET; t += gsz) {
    if (t < E0) atomicAdd(&cnt[d0[t]], 1);
    else if (t < E0 + E1) atomicAdd(&cnt[60000 + d1[t - E0]], 1);
    else atomicAdd(&cnt[66000 + d2[t - E0 - E1]], 1);
  }
  grid.sync();

  // ---- Phase C: per-tile scan (prefix read straight from cnt) ----
  if (blockIdx.x < 132) {
    const TileGeom g = tile_geom(blockIdx.x);
    int* row = (blockIdx.x < 118) ? (iw + ROW0_OFF)
             : (blockIdx.x < 130) ? (iw + ROW1_OFF) : (iw + ROW2_OFF);
    int* cur = (blockIdx.x < 118) ? (iw + CUR0_OFF)
             : (blockIdx.x < 130) ? (iw + CUR1_OFF) : (iw + CUR2_OFF);
    int p = 0;
    const int lim = g.tin * 512;
    for (int i = tid; i < lim; i += 256) p += cnt[g.goff + i];
    sld[tid] = p;
    __syncthreads();
    for (int off = 128; off; off >>= 1) {
      if (tid < off) sld[tid] += sld[tid + off];
      __syncthreads();
    }
    const int pref = sld[0];
    __syncthreads();
    const int i0 = g.tin * 512 + 2 * tid;
    const int e0 = (i0 < g.n) ? cnt[g.goff + i0] : 0;
    const int e1 = (i0 + 1 < g.n) ? cnt[g.goff + i0 + 1] : 0;
    sld[tid] = e0 + e1;
    __syncthreads();
    for (int off = 1; off < 256; off <<= 1) {
      int v = (tid >= off) ? sld[tid - off] : 0;
      __syncthreads();
      sld[tid] += v;
      __syncthreads();
    }
    const int excl = sld[tid] - (e0 + e1);
    const int o0v = pref + excl;
    const int o1v = o0v + e0;
    if (i0 < g.n) { row[i0] = o0v; cur[i0] = o0v; }
    if (i0 + 1 < g.n) { row[i0 + 1] = o1v; cur[i0 + 1] = o1v; }
    if (g.tin == g.T - 1 && tid == 255) row[g.n] = pref + sld[255];
  }
  grid.sync();

  // ---- Phase D: fill src_sorted ----
  int* u0 = iw + CUR0_OFF; int* u1 = iw + CUR1_OFF; int* u2 = iw + CUR2_OFF;
  int* o0 = iw + SS0_OFF;  int* o1 = iw + SS1_OFF;  int* o2 = iw + SS2_OFF;
  for (int t = gtid; t < ET; t += gsz) {
    if (t < E0) {
      int pos = atomicAdd(&u0[d0[t]], 1);
      o0[pos] = s0[t];
    } else if (t < E0 + E1) {
      int e = t - E0;
      int pos = atomicAdd(&u1[d1[e]], 1);
      o1[pos] = s1[e];
    } else {
      int e = t - E0 - E1;
      int pos = atomicAdd(&u2[d2[e]], 1);
      o2[pos] = s2[e];
    }
  }
}

// ------------- gather-mean + self-row conversion (layer 0, f32 in) -------------
template <int D, int PITCH, int XOFF>
__global__ __launch_bounds__(256) void gather_fused_k(
    const float* __restrict__ x, const float* __restrict__ xt,
    const int* __restrict__ ss, const int* __restrict__ rs,
    unsigned short* __restrict__ am, int n) {
  int idx = blockIdx.x * 256 + threadIdx.x;
  int w = idx >> 6;
  int f = idx & 63;
  if (w >= n) return;
  const int lo = rs[w];
  const int hi = rs[w + 1];
  constexpr int NR = (D + 63) / 64;
  float acc[NR];
#pragma unroll
  for (int r = 0; r < NR; ++r) acc[r] = 0.f;
  int e = lo;
  for (; e + 4 <= hi; e += 4) {
    const float* p0 = x + (size_t)ss[e] * D;
    const float* p1 = x + (size_t)ss[e + 1] * D;
    const float* p2 = x + (size_t)ss[e + 2] * D;
    const float* p3 = x + (size_t)ss[e + 3] * D;
#pragma unroll
    for (int r = 0; r < NR; ++r) {
      int k = f + 64 * r;
      if (k < D) acc[r] += (p0[k] + p1[k]) + (p2[k] + p3[k]);
    }
  }
  for (; e < hi; ++e) {
    const float* p0 = x + (size_t)ss[e] * D;
#pragma unroll
    for (int r = 0; r < NR; ++r) {
      int k = f + 64 * r;
      if (k < D) acc[r] += p0[k];
    }
  }
  const float inv = 1.f / (float)max(hi - lo, 1);
  unsigned short* arow = am + (size_t)w * PITCH;
#pragma unroll
  for (int r = 0; r < NR; ++r) {
    int k = f + 64 * r;
    if (k < D) arow[k] = f2bf(acc[r] * inv);
  }
  const float* xrow = xt + (size_t)w * D;
#pragma unroll
  for (int r = 0; r < NR; ++r) {
    int k = f + 64 * r;
    if (k < D) arow[XOFF + k] = f2bf(xrow[k]);
  }
}

// ------------- gather-mean, bf16 input (layer 1), writes mean only -------------
__global__ __launch_bounds__(256) void gather_mean_b16_k(
    const unsigned short* __restrict__ xb, const int* __restrict__ ss,
    const int* __restrict__ rs, unsigned short* __restrict__ mean, int n) {
  int idx = blockIdx.x * 256 + threadIdx.x;
  int w = idx >> 6;
  int f = idx & 63;
  if (w >= n) return;
  const int lo = rs[w];
  const int hi = rs[w + 1];
  float a0 = 0.f, a1 = 0.f, a2 = 0.f, a3 = 0.f;
  int e = lo;
  for (; e + 2 <= hi; e += 2) {
    const unsigned short* p0 = xb + (size_t)ss[e] * 256;
    const unsigned short* p1 = xb + (size_t)ss[e + 1] * 256;
    a0 += bf2f(p0[f]) + bf2f(p1[f]);
    a1 += bf2f(p0[f + 64]) + bf2f(p1[f + 64]);
    a2 += bf2f(p0[f + 128]) + bf2f(p1[f + 128]);
    a3 += bf2f(p0[f + 192]) + bf2f(p1[f + 192]);
  }
  for (; e < hi; ++e) {
    const unsigned short* p0 = xb + (size_t)ss[e] * 256;
    a0 += bf2f(p0[f]); a1 += bf2f(p0[f + 64]);
    a2 += bf2f(p0[f + 128]); a3 += bf2f(p0[f + 192]);
  }
  const float inv = 1.f / (float)max(hi - lo, 1);
  unsigned short* mr = mean + (size_t)w * 256;
  mr[f] = f2bf(a0 * inv);
  mr[f + 64] = f2bf(a1 * inv);
  mr[f + 128] = f2bf(a2 * inv);
  mr[f + 192] = f2bf(a3 * inv);
}

// ------------- MFMA GEMM, two-pointer A, optional bf16 out -------------
template <int KPAD, int C1CH, int MBLK, bool RELU, bool OUTBF>
__global__ __launch_bounds__(256) void gemm_mfma_k(
    const unsigned short* __restrict__ A1, const unsigned short* __restrict__ A2,
    const unsigned short* __restrict__ Bp, const float* __restrict__ bias,
    void* __restrict__ outv, int M, int p1, int p2) {
  constexpr int LDA = KPAD + 8;
  constexpr int CPR = KPAD / 8;
  constexpr int RT = MBLK / 16;
  constexpr int NKC = KPAD / 32;
  __shared__ unsigned short As[MBLK * LDA];

  const int row0 = blockIdx.x * MBLK;
  for (int t = threadIdx.x; t < MBLK * CPR; t += 256) {
    int r = t / CPR;
    int c = t - r * CPR;
    const unsigned short* src = (c < C1CH)
        ? (A1 + (size_t)(row0 + r) * p1 + c * 8)
        : (A2 + (size_t)(row0 + r) * p2 + (c - C1CH) * 8);
    *reinterpret_cast<uint4*>(&As[r * LDA + c * 8]) =
        *reinterpret_cast<const uint4*>(src);
  }
  __syncthreads();

  const int wid = threadIdx.x >> 6;
  const int l = threadIdx.x & 63;
  const int l15 = l & 15;
  const int lhi = l >> 4;

  f32x4 acc[RT][4];
#pragma unroll
  for (int rt = 0; rt < RT; ++rt)
#pragma unroll
    for (int ct = 0; ct < 4; ++ct) acc[rt][ct] = (f32x4){0.f, 0.f, 0.f, 0.f};

  for (int kc = 0; kc < NKC; ++kc) {
    bf16x8 a[RT], b[4];
#pragma unroll
    for (int rt = 0; rt < RT; ++rt)
      a[rt] = *reinterpret_cast<const bf16x8*>(
          &As[(rt * 16 + l15) * LDA + kc * 32 + lhi * 8]);
#pragma unroll
    for (int ct = 0; ct < 4; ++ct) {
      int n = wid * 64 + ct * 16 + l15;
      b[ct] = *reinterpret_cast<const bf16x8*>(
          Bp + ((size_t)(kc * 4 + lhi) * 256 + n) * 8);
    }
#pragma unroll
    for (int rt = 0; rt < RT; ++rt)
#pragma unroll
      for (int ct = 0; ct < 4; ++ct)
        acc[rt][ct] = __builtin_amdgcn_mfma_f32_16x16x32_bf16(a[rt], b[ct],
                                                              acc[rt][ct], 0, 0, 0);
  }

#pragma unroll
  for (int rt = 0; rt < RT; ++rt) {
#pragma unroll
    for (int ct = 0; ct < 4; ++ct) {
      int col = wid * 64 + ct * 16 + l15;
      float bv = bias[col];
#pragma unroll
      for (int r = 0; r < 4; ++r) {
        int row = row0 + rt * 16 + lhi * 4 + r;
        if (row < M) {
          float v = acc[rt][ct][r] + bv;
          if (RELU) v = fmaxf(v, 0.f);
          if (OUTBF)
            ((unsigned short*)outv)[(size_t)row * 256 + col] = f2bf(v);
          else
            ((float*)outv)[(size_t)row * 256 + col] = v;
        }
      }
    }
  }
}

// ------- final: fused gather2 + dual GEMM (512 -> 47) + log_softmax -------
__global__ __launch_bounds__(64) void final_fused_k(
    const float* __restrict__ h1, const int* __restrict__ ss,
    const int* __restrict__ rs, const float* __restrict__ Wl,
    const float* __restrict__ Wr, const float* __restrict__ bb,
    float* __restrict__ out) {
  __shared__ float sm[4][256];
  __shared__ float sx[4][256];
  const int i0 = blockIdx.x * 4;
  const int f = threadIdx.x;
#pragma unroll
  for (int r = 0; r < 4; ++r) {
    const int i = i0 + r;
    const int lo = rs[i];
    const int hi = rs[i + 1];
    float a0 = 0.f, a1 = 0.f, a2 = 0.f, a3 = 0.f;
    for (int e = lo; e < hi; ++e) {
      const float* p = h1 + (size_t)ss[e] * 256;
      a0 += p[f]; a1 += p[f + 64]; a2 += p[f + 128]; a3 += p[f + 192];
    }
    const float inv = 1.f / (float)max(hi - lo, 1);
    sm[r][f] = a0 * inv; sm[r][f + 64] = a1 * inv;
    sm[r][f + 128] = a2 * inv; sm[r][f + 192] = a3 * inv;
    const float* q = h1 + (size_t)i * 256;
    sx[r][f] = q[f]; sx[r][f + 64] = q[f + 64];
    sx[r][f + 128] = q[f + 128]; sx[r][f + 192] = q[f + 192];
  }
  __syncthreads();

  const int j = f;
  float acc[4] = {-1e30f, -1e30f, -1e30f, -1e30f};
  if (j < 47) {
    float b = bb[j];
    acc[0] = b; acc[1] = b; acc[2] = b; acc[3] = b;
    for (int k = 0; k < 256; ++k) {
      float wl = Wl[k * 47 + j];
      float wr = Wr[k * 47 + j];
#pragma unroll
      for (int r = 0; r < 4; ++r) acc[r] += sm[r][k] * wl + sx[r][k] * wr;
    }
  }
#pragma unroll
  for (int r = 0; r < 4; ++r) {
    float m = acc[r];
#pragma unroll
    for (int off = 32; off; off >>= 1) m = fmaxf(m, __shfl_xor(m, off));
    float e = (j < 47) ? expf(acc[r] - m) : 0.f;
    float s = e;
#pragma unroll
    for (int off = 32; off; off >>= 1) s += __shfl_xor(s, off);
    if (j < 47) out[(size_t)(i0 + r) * 47 + j] = acc[r] - m - logf(s);
  }
}

extern "C" void kernel_launch(void* const* d_in, const int* in_sizes, int n_in,
                              void* d_out, int out_size, void* d_ws, size_t ws_size,
                              hipStream_t stream) {
  const float* x    = (const float*)d_in[0];
  const int*   src0 = (const int*)d_in[1];
  const int*   dst0 = (const int*)d_in[2];
  const int*   src1 = (const int*)d_in[3];
  const int*   dst1 = (const int*)d_in[4];
  const int*   src2 = (const int*)d_in[5];
  const int*   dst2 = (const int*)d_in[6];
  const float* Wl0  = (const float*)d_in[7];
  const float* Wr0  = (const float*)d_in[8];
  const float* b0   = (const float*)d_in[9];
  const float* Wl1  = (const float*)d_in[10];
  const float* Wr1  = (const float*)d_in[11];
  const float* b1   = (const float*)d_in[12];
  const float* Wl2  = (const float*)d_in[13];
  const float* Wr2  = (const float*)d_in[14];
  const float* b2   = (const float*)d_in[15];
  float* out = (float*)d_out;

  int E0 = in_sizes[1];  // 900000
  int E1 = in_sizes[3];  // 60000
  int E2 = in_sizes[5];  // 5120
  const int N0 = 60000, N1 = 6000, N2 = 1024;

  // ---- workspace carve-up (bytes) ----
  char* base = (char*)d_ws;
  unsigned short* am0  = (unsigned short*)(base);            // 60032 x 224 bf16
  unsigned short* bm0  = (unsigned short*)(base + 26894336); // 28x256x8 bf16
  unsigned short* h0b  = (unsigned short*)(base + 27009024); // 60032 x 256 bf16
  unsigned short* mean1= (unsigned short*)(base + 57745408); // 6016 x 256 bf16
  unsigned short* bm1  = (unsigned short*)(base + 60825600); // 64x256x8 bf16
  float* h1            = (float*)(base + 61087744);          // 6016 x 256 f32
  int* iw              = (int*)(base + 67248128);
  int* row0 = iw + ROW0_OFF;
  int* row1 = iw + ROW1_OFF;
  int* row2 = iw + ROW2_OFF;
  int* ss0  = iw + SS0_OFF;
  int* ss1  = iw + SS1_OFF;
  int* ss2  = iw + SS2_OFF;

  // ---- cooperative CSR build + weight pack (one dispatch) ----
  void* kargs[] = {
    (void*)&dst0, (void*)&dst1, (void*)&dst2,
    (void*)&src0, (void*)&src1, (void*)&src2,
    (void*)&iw,
    (void*)&Wl0, (void*)&Wr0, (void*)&bm0,
    (void*)&Wl1, (void*)&Wr1, (void*)&bm1,
    (void*)&E0, (void*)&E1, (void*)&E2,
  };
  hipLaunchCooperativeKernel((void*)csr_coop_k, dim3(1024), dim3(256),
                             kargs, 0, stream);

  // ---- Layer 0 ----
  gather_fused_k<100, 224, 112><<<(N0 * 64 + 255) / 256, 256, 0, stream>>>(
      x, x, ss0, row0, am0, N0);
  gemm_mfma_k<224, 28, 64, true, true><<<(N0 + 63) / 64, 256, 0, stream>>>(
      am0, am0, bm0, b0, (void*)h0b, N0, 224, 224);

  // ---- Layer 1 ----
  gather_mean_b16_k<<<(N1 * 64 + 255) / 256, 256, 0, stream>>>(
      h0b, ss1, row1, mean1, N1);
  gemm_mfma_k<512, 32, 32, true, false><<<(N1 + 31) / 32, 256, 0, stream>>>(
      mean1, h0b, bm1, b1, (void*)h1, N1, 256, 256);

  // ---- Layer 2 (fused final) ----
  final_fused_k<<<N2 / 4, 64, 0, stream>>>(h1, ss2, row2, Wl2, Wr2, b2, out);
}

// Round 9
// 308.566 us; speedup vs baseline: 1.9580x; 1.9580x over previous
//
#include <hip/hip_runtime.h>
#include <hip/hip_bf16.h>

// GraphSAGE 3-layer. Round 9: split kernels (coop reverted) + bf16-x pipeline.
//  memset(cnt), histrank(+convA), tilesum+pack, scanwrite, fillscatter(+convB),
//  gather0(bf16), gemm0(bf16 out), gather1(bf16), gemm1, final = 10 dispatches.
// x is converted to bf16 (xb) inside the latency-bound CSR kernels (mixed-block
// overlap); gather0 reads bf16 rows (half the random-read bytes).

typedef short bf16x8 __attribute__((ext_vector_type(8)));
typedef float f32x4 __attribute__((ext_vector_type(4)));

static __device__ __forceinline__ unsigned short f2bf(float f) {
  unsigned u = __float_as_uint(f);
  unsigned r = u + 0x7FFFu + ((u >> 16) & 1u);  // RNE
  return (unsigned short)(r >> 16);
}
static __device__ __forceinline__ float bf2f_lo(unsigned u) {
  return __uint_as_float(u << 16);
}
static __device__ __forceinline__ float bf2f_hi(unsigned u) {
  return __uint_as_float(u & 0xFFFF0000u);
}
static __device__ __forceinline__ unsigned packbf(float lo, float hi) {
  return ((unsigned)f2bf(hi) << 16) | (unsigned)f2bf(lo);
}

// ---- sizes ----
#define E0C 900000
#define E1C 60000
#define E2C 5120
#define ETC 965120
#define NU  45000000   // uints in xb (900000*50)
#define NUA 3000000    // uints duplicated into am0 x-part (60000*50)
#define CSPLIT 22000000
#define CB1 1408       // conv blocks in histrank
#define HB  3770       // hist blocks (965120/256)
#define CB2 1472       // conv blocks in fillscatter

// ---- int-workspace offsets ----
#define ROW0_OFF 0
#define ROW1_OFF 60001
#define ROW2_OFF 66002
#define CNT_OFF  67027
#define RANK_OFF 134051
#define SS0_OFF  1099171
#define SS1_OFF  1999171
#define SS2_OFF  2059171
#define TSUM_OFF 2064291

struct TileGeom { int tin, goff, n, tbeg, T; };
static __device__ __forceinline__ TileGeom tile_geom(int b) {
  TileGeom g;
  if (b < 118)      { g.tin = b;       g.goff = 0;     g.n = 60000; g.tbeg = 0;   g.T = 118; }
  else if (b < 130) { g.tin = b - 118; g.goff = 60000; g.n = 6000;  g.tbeg = 118; g.T = 12; }
  else              { g.tin = b - 130; g.goff = 66000; g.n = 1024;  g.tbeg = 130; g.T = 2; }
  return g;
}

// ---------- hist (+rank) with first half of x conversion ----------
__global__ __launch_bounds__(256) void histrank_k(
    const int* __restrict__ d0, const int* __restrict__ d1, const int* __restrict__ d2,
    int* __restrict__ cnt, int* __restrict__ rank,
    const float* __restrict__ x, unsigned* __restrict__ xb,
    unsigned* __restrict__ am0u) {
  const int b = blockIdx.x;
  const int tid = threadIdx.x;
  if (b < CB1) {
    for (int i = b * 256 + tid; i < CSPLIT; i += CB1 * 256) {
      const float2 v = ((const float2*)x)[i];
      const unsigned u = packbf(v.x, v.y);
      xb[i] = u;
      if (i < NUA) {
        int row = i / 50;
        int c = i - row * 50;
        am0u[row * 112 + 56 + c] = u;
      }
    }
  } else {
    int t = (b - CB1) * 256 + tid;
    if (t < E0C) {
      rank[t] = atomicAdd(&cnt[d0[t]], 1);
    } else if (t < E0C + E1C) {
      int e = t - E0C;
      rank[t] = atomicAdd(&cnt[60000 + d1[e]], 1);
    } else if (t < ETC) {
      int e = t - E0C - E1C;
      rank[t] = atomicAdd(&cnt[66000 + d2[e]], 1);
    }
  }
}

// ---------- per-tile sums + weight packing ----------
__global__ __launch_bounds__(256) void tilesum_pack_k(
    const int* __restrict__ cnt, int* __restrict__ tsum,
    const float* __restrict__ Wl0, const float* __restrict__ Wr0,
    unsigned short* __restrict__ bm0,
    const float* __restrict__ Wl1, const float* __restrict__ Wr1,
    unsigned short* __restrict__ bm1) {
  const int b = blockIdx.x;
  const int tid = threadIdx.x;
  if (b < 132) {
    __shared__ int red[256];
    const TileGeom g = tile_geom(b);
    const int i0 = g.tin * 512 + 2 * tid;
    int s = 0;
    if (i0 < g.n) s += cnt[g.goff + i0];
    if (i0 + 1 < g.n) s += cnt[g.goff + i0 + 1];
    red[tid] = s;
    __syncthreads();
    for (int off = 128; off; off >>= 1) {
      if (tid < off) red[tid] += red[tid + off];
      __syncthreads();
    }
    if (tid == 0) tsum[b] = red[0];
  } else {
    int j = b - 132;
    int n = tid;
    if (j < 224) {
      int k = j;
      float v = 0.f;
      if (k < 100) v = Wl0[(size_t)k * 256 + n];
      else if (k >= 112 && k < 212) v = Wr0[(size_t)(k - 112) * 256 + n];
      bm0[(((size_t)(k >> 3) * 256) + n) * 8 + (k & 7)] = f2bf(v);
    } else {
      int k = j - 224;
      float v = (k < 256) ? Wl1[(size_t)k * 256 + n] : Wr1[(size_t)(k - 256) * 256 + n];
      bm1[(((size_t)(k >> 3) * 256) + n) * 8 + (k & 7)] = f2bf(v);
    }
  }
}

// ---------- per-tile scan, writes row_start only ----------
__global__ __launch_bounds__(256) void scanwrite_k(
    const int* __restrict__ cnt, const int* __restrict__ tsum,
    int* __restrict__ row0, int* __restrict__ row1, int* __restrict__ row2) {
  __shared__ int sc[256];
  const int b = blockIdx.x;
  const TileGeom g = tile_geom(b);
  const int tid = threadIdx.x;
  int* row = (b < 118) ? row0 : (b < 130 ? row1 : row2);

  int p = 0;
  for (int t = g.tbeg + tid; t < b; t += 256) p += tsum[t];
  sc[tid] = p;
  __syncthreads();
  for (int off = 128; off; off >>= 1) {
    if (tid < off) sc[tid] += sc[tid + off];
    __syncthreads();
  }
  const int pref = sc[0];
  __syncthreads();

  const int i0 = g.tin * 512 + 2 * tid;
  const int e0 = (i0 < g.n) ? cnt[g.goff + i0] : 0;
  const int e1 = (i0 + 1 < g.n) ? cnt[g.goff + i0 + 1] : 0;
  sc[tid] = e0 + e1;
  __syncthreads();
  for (int off = 1; off < 256; off <<= 1) {
    int v = (tid >= off) ? sc[tid - off] : 0;
    __syncthreads();
    sc[tid] += v;
    __syncthreads();
  }
  const int excl = sc[tid] - (e0 + e1);
  const int o0 = pref + excl;
  const int o1 = o0 + e0;
  if (i0 < g.n) row[i0] = o0;
  if (i0 + 1 < g.n) row[i0 + 1] = o1;
  if (g.tin == g.T - 1 && tid == 255) row[g.n] = pref + sc[255];
}

// ---------- atomic-free fill (rank-based) + second half of conversion ----------
__global__ __launch_bounds__(256) void fillscatter_k(
    const int* __restrict__ d0, const int* __restrict__ d1, const int* __restrict__ d2,
    const int* __restrict__ s0, const int* __restrict__ s1, const int* __restrict__ s2,
    const int* __restrict__ row0, const int* __restrict__ row1,
    const int* __restrict__ row2, const int* __restrict__ rank,
    int* __restrict__ o0, int* __restrict__ o1, int* __restrict__ o2,
    const float* __restrict__ x, unsigned* __restrict__ xb) {
  const int b = blockIdx.x;
  const int tid = threadIdx.x;
  if (b < CB2) {
    for (int i = CSPLIT + b * 256 + tid; i < NU; i += CB2 * 256) {
      const float2 v = ((const float2*)x)[i];
      xb[i] = packbf(v.x, v.y);
    }
  } else {
    int t = (b - CB2) * 256 + tid;
    if (t < E0C) {
      o0[row0[d0[t]] + rank[t]] = s0[t];
    } else if (t < E0C + E1C) {
      int e = t - E0C;
      o1[row1[d1[e]] + rank[t]] = s1[e];
    } else if (t < ETC) {
      int e = t - E0C - E1C;
      o2[row2[d2[e]] + rank[t]] = s2[e];
    }
  }
}

// ---------- gather-mean layer 0: bf16 rows (50 uints), mean-part only ----------
__global__ __launch_bounds__(256) void gather0_k(
    const unsigned* __restrict__ xb, const int* __restrict__ ss,
    const int* __restrict__ rs, unsigned* __restrict__ am0u, int n) {
  int idx = blockIdx.x * 256 + threadIdx.x;
  int w = idx >> 6;
  int f = idx & 63;
  if (w >= n) return;
  const int lo = rs[w];
  const int hi = rs[w + 1];
  float aLo = 0.f, aHi = 0.f;
  const bool act = f < 50;
  int e = lo;
  for (; e + 4 <= hi; e += 4) {
    const unsigned* p0 = xb + (size_t)ss[e] * 50;
    const unsigned* p1 = xb + (size_t)ss[e + 1] * 50;
    const unsigned* p2 = xb + (size_t)ss[e + 2] * 50;
    const unsigned* p3 = xb + (size_t)ss[e + 3] * 50;
    if (act) {
      unsigned u0 = p0[f], u1 = p1[f], u2 = p2[f], u3 = p3[f];
      aLo += (bf2f_lo(u0) + bf2f_lo(u1)) + (bf2f_lo(u2) + bf2f_lo(u3));
      aHi += (bf2f_hi(u0) + bf2f_hi(u1)) + (bf2f_hi(u2) + bf2f_hi(u3));
    }
  }
  for (; e < hi; ++e) {
    const unsigned* p0 = xb + (size_t)ss[e] * 50;
    if (act) {
      unsigned u0 = p0[f];
      aLo += bf2f_lo(u0);
      aHi += bf2f_hi(u0);
    }
  }
  const float inv = 1.f / (float)max(hi - lo, 1);
  if (act) am0u[(size_t)w * 112 + f] = packbf(aLo * inv, aHi * inv);
}

// ---------- gather-mean layer 1: bf16 rows (128 uints) ----------
__global__ __launch_bounds__(256) void gather_mean_b16_k(
    const unsigned* __restrict__ xbu, const int* __restrict__ ss,
    const int* __restrict__ rs, unsigned* __restrict__ meanu, int n) {
  int idx = blockIdx.x * 256 + threadIdx.x;
  int w = idx >> 6;
  int f = idx & 63;
  if (w >= n) return;
  const int lo = rs[w];
  const int hi = rs[w + 1];
  float a0l = 0.f, a0h = 0.f, a1l = 0.f, a1h = 0.f;
  int e = lo;
  for (; e + 2 <= hi; e += 2) {
    const unsigned* p0 = xbu + (size_t)ss[e] * 128;
    const unsigned* p1 = xbu + (size_t)ss[e + 1] * 128;
    unsigned u0a = p0[f], u0b = p0[f + 64];
    unsigned u1a = p1[f], u1b = p1[f + 64];
    a0l += bf2f_lo(u0a) + bf2f_lo(u1a);
    a0h += bf2f_hi(u0a) + bf2f_hi(u1a);
    a1l += bf2f_lo(u0b) + bf2f_lo(u1b);
    a1h += bf2f_hi(u0b) + bf2f_hi(u1b);
  }
  for (; e < hi; ++e) {
    const unsigned* p0 = xbu + (size_t)ss[e] * 128;
    unsigned ua = p0[f], ub = p0[f + 64];
    a0l += bf2f_lo(ua); a0h += bf2f_hi(ua);
    a1l += bf2f_lo(ub); a1h += bf2f_hi(ub);
  }
  const float inv = 1.f / (float)max(hi - lo, 1);
  meanu[(size_t)w * 128 + f] = packbf(a0l * inv, a0h * inv);
  meanu[(size_t)w * 128 + f + 64] = packbf(a1l * inv, a1h * inv);
}

// ---------- MFMA GEMM, two-pointer A, optional bf16 out ----------
template <int KPAD, int C1CH, int MBLK, bool RELU, bool OUTBF>
__global__ __launch_bounds__(256) void gemm_mfma_k(
    const unsigned short* __restrict__ A1, const unsigned short* __restrict__ A2,
    const unsigned short* __restrict__ Bp, const float* __restrict__ bias,
    void* __restrict__ outv, int M, int p1, int p2) {
  constexpr int LDA = KPAD + 8;
  constexpr int CPR = KPAD / 8;
  constexpr int RT = MBLK / 16;
  constexpr int NKC = KPAD / 32;
  __shared__ unsigned short As[MBLK * LDA];

  const int row0 = blockIdx.x * MBLK;
  for (int t = threadIdx.x; t < MBLK * CPR; t += 256) {
    int r = t / CPR;
    int c = t - r * CPR;
    const unsigned short* src = (c < C1CH)
        ? (A1 + (size_t)(row0 + r) * p1 + c * 8)
        : (A2 + (size_t)(row0 + r) * p2 + (c - C1CH) * 8);
    *reinterpret_cast<uint4*>(&As[r * LDA + c * 8]) =
        *reinterpret_cast<const uint4*>(src);
  }
  __syncthreads();

  const int wid = threadIdx.x >> 6;
  const int l = threadIdx.x & 63;
  const int l15 = l & 15;
  const int lhi = l >> 4;

  f32x4 acc[RT][4];
#pragma unroll
  for (int rt = 0; rt < RT; ++rt)
#pragma unroll
    for (int ct = 0; ct < 4; ++ct) acc[rt][ct] = (f32x4){0.f, 0.f, 0.f, 0.f};

  for (int kc = 0; kc < NKC; ++kc) {
    bf16x8 a[RT], b[4];
#pragma unroll
    for (int rt = 0; rt < RT; ++rt)
      a[rt] = *reinterpret_cast<const bf16x8*>(
          &As[(rt * 16 + l15) * LDA + kc * 32 + lhi * 8]);
#pragma unroll
    for (int ct = 0; ct < 4; ++ct) {
      int n = wid * 64 + ct * 16 + l15;
      b[ct] = *reinterpret_cast<const bf16x8*>(
          Bp + ((size_t)(kc * 4 + lhi) * 256 + n) * 8);
    }
#pragma unroll
    for (int rt = 0; rt < RT; ++rt)
#pragma unroll
      for (int ct = 0; ct < 4; ++ct)
        acc[rt][ct] = __builtin_amdgcn_mfma_f32_16x16x32_bf16(a[rt], b[ct],
                                                              acc[rt][ct], 0, 0, 0);
  }

#pragma unroll
  for (int rt = 0; rt < RT; ++rt) {
#pragma unroll
    for (int ct = 0; ct < 4; ++ct) {
      int col = wid * 64 + ct * 16 + l15;
      float bv = bias[col];
#pragma unroll
      for (int r = 0; r < 4; ++r) {
        int row = row0 + rt * 16 + lhi * 4 + r;
        if (row < M) {
          float v = acc[rt][ct][r] + bv;
          if (RELU) v = fmaxf(v, 0.f);
          if (OUTBF)
            ((unsigned short*)outv)[(size_t)row * 256 + col] = f2bf(v);
          else
            ((float*)outv)[(size_t)row * 256 + col] = v;
        }
      }
    }
  }
}

// ---------- final: fused gather2 + dual GEMM (512 -> 47) + log_softmax ----------
__global__ __launch_bounds__(64) void final_fused_k(
    const float* __restrict__ h1, const int* __restrict__ ss,
    const int* __restrict__ rs, const float* __restrict__ Wl,
    const float* __restrict__ Wr, const float* __restrict__ bb,
    float* __restrict__ out) {
  __shared__ float sm[4][256];
  __shared__ float sx[4][256];
  const int i0 = blockIdx.x * 4;
  const int f = threadIdx.x;
#pragma unroll
  for (int r = 0; r < 4; ++r) {
    const int i = i0 + r;
    const int lo = rs[i];
    const int hi = rs[i + 1];
    float a0 = 0.f, a1 = 0.f, a2 = 0.f, a3 = 0.f;
    for (int e = lo; e < hi; ++e) {
      const float* p = h1 + (size_t)ss[e] * 256;
      a0 += p[f]; a1 += p[f + 64]; a2 += p[f + 128]; a3 += p[f + 192];
    }
    const float inv = 1.f / (float)max(hi - lo, 1);
    sm[r][f] = a0 * inv; sm[r][f + 64] = a1 * inv;
    sm[r][f + 128] = a2 * inv; sm[r][f + 192] = a3 * inv;
    const float* q = h1 + (size_t)i * 256;
    sx[r][f] = q[f]; sx[r][f + 64] = q[f + 64];
    sx[r][f + 128] = q[f + 128]; sx[r][f + 192] = q[f + 192];
  }
  __syncthreads();

  const int j = f;
  float acc[4] = {-1e30f, -1e30f, -1e30f, -1e30f};
  if (j < 47) {
    float b = bb[j];
    acc[0] = b; acc[1] = b; acc[2] = b; acc[3] = b;
    for (int k = 0; k < 256; ++k) {
      float wl = Wl[k * 47 + j];
      float wr = Wr[k * 47 + j];
#pragma unroll
      for (int r = 0; r < 4; ++r) acc[r] += sm[r][k] * wl + sx[r][k] * wr;
    }
  }
#pragma unroll
  for (int r = 0; r < 4; ++r) {
    float m = acc[r];
#pragma unroll
    for (int off = 32; off; off >>= 1) m = fmaxf(m, __shfl_xor(m, off));
    float e = (j < 47) ? expf(acc[r] - m) : 0.f;
    float s = e;
#pragma unroll
    for (int off = 32; off; off >>= 1) s += __shfl_xor(s, off);
    if (j < 47) out[(size_t)(i0 + r) * 47 + j] = acc[r] - m - logf(s);
  }
}

extern "C" void kernel_launch(void* const* d_in, const int* in_sizes, int n_in,
                              void* d_out, int out_size, void* d_ws, size_t ws_size,
                              hipStream_t stream) {
  const float* x    = (const float*)d_in[0];
  const int*   src0 = (const int*)d_in[1];
  const int*   dst0 = (const int*)d_in[2];
  const int*   src1 = (const int*)d_in[3];
  const int*   dst1 = (const int*)d_in[4];
  const int*   src2 = (const int*)d_in[5];
  const int*   dst2 = (const int*)d_in[6];
  const float* Wl0  = (const float*)d_in[7];
  const float* Wr0  = (const float*)d_in[8];
  const float* b0   = (const float*)d_in[9];
  const float* Wl1  = (const float*)d_in[10];
  const float* Wr1  = (const float*)d_in[11];
  const float* b1   = (const float*)d_in[12];
  const float* Wl2  = (const float*)d_in[13];
  const float* Wr2  = (const float*)d_in[14];
  const float* b2   = (const float*)d_in[15];
  float* out = (float*)d_out;

  const int N0 = 60000, N1 = 6000, N2 = 1024;

  // ---- workspace carve-up (bytes) ----
  char* base = (char*)d_ws;
  unsigned short* am0  = (unsigned short*)(base);            // 60032 x 224 bf16
  unsigned*       am0u = (unsigned*)(base);
  unsigned short* bm0  = (unsigned short*)(base + 26894336); // 28x256x8 bf16
  unsigned short* h0b  = (unsigned short*)(base + 27009024); // 60032 x 256 bf16
  unsigned*       h0bu = (unsigned*)(base + 27009024);
  unsigned short* mean1= (unsigned short*)(base + 57745408); // 6016 x 256 bf16
  unsigned*       mean1u=(unsigned*)(base + 57745408);
  unsigned short* bm1  = (unsigned short*)(base + 60825600); // 64x256x8 bf16
  float* h1            = (float*)(base + 61087744);          // 6016 x 256 f32
  unsigned* xb         = (unsigned*)(base + 67248128);       // 900000 x 50 uints
  int* iw              = (int*)(base + 247248128);
  int* row0 = iw + ROW0_OFF;
  int* row1 = iw + ROW1_OFF;
  int* row2 = iw + ROW2_OFF;
  int* cnt  = iw + CNT_OFF;
  int* rank = iw + RANK_OFF;
  int* ss0  = iw + SS0_OFF;
  int* ss1  = iw + SS1_OFF;
  int* ss2  = iw + SS2_OFF;
  int* tsum = iw + TSUM_OFF;

  // ---- CSR build + conversion (mixed-block overlap) ----
  hipMemsetAsync(cnt, 0, (size_t)67024 * sizeof(int), stream);
  histrank_k<<<CB1 + HB, 256, 0, stream>>>(dst0, dst1, dst2, cnt, rank,
                                           x, xb, am0u);
  tilesum_pack_k<<<132 + 736, 256, 0, stream>>>(cnt, tsum, Wl0, Wr0, bm0,
                                                Wl1, Wr1, bm1);
  scanwrite_k<<<132, 256, 0, stream>>>(cnt, tsum, row0, row1, row2);
  fillscatter_k<<<CB2 + HB, 256, 0, stream>>>(dst0, dst1, dst2, src0, src1, src2,
                                              row0, row1, row2, rank,
                                              ss0, ss1, ss2, x, xb);

  // ---- Layer 0 ----
  gather0_k<<<(N0 * 64 + 255) / 256, 256, 0, stream>>>(xb, ss0, row0, am0u, N0);
  gemm_mfma_k<224, 28, 64, true, true><<<(N0 + 63) / 64, 256, 0, stream>>>(
      am0, am0, bm0, b0, (void*)h0b, N0, 224, 224);

  // ---- Layer 1 ----
  gather_mean_b16_k<<<(N1 * 64 + 255) / 256, 256, 0, stream>>>(
      h0bu, ss1, row1, mean1u, N1);
  gemm_mfma_k<512, 32, 32, true, false><<<(N1 + 31) / 32, 256, 0, stream>>>(
      mean1, h0b, bm1, b1, (void*)h1, N1, 256, 256);

  // ---- Layer 2 (fused final) ----
  final_fused_k<<<N2 / 4, 64, 0, stream>>>(h1, ss2, row2, Wl2, Wr2, b2, out);
}